// Round 4
// baseline (299.535 us; speedup 1.0000x reference)
//
#include <hip/hip_runtime.h>
#include <hip/hip_bf16.h>

typedef __attribute__((ext_vector_type(8))) __bf16 bf16x8;
typedef __attribute__((ext_vector_type(4))) float f32x4;

#define N_SEQ   2048
#define N_BATCH 32
#define DIM_U   1024
#define NROWS   65536
#define MA_ELEMS ((size_t)NROWS * DIM_U) /* 67108864 */

__device__ __forceinline__ float tanh_fast(float x) {
    x = fminf(fmaxf(x, -15.f), 15.f);
    float e = __expf(2.f * x);
    return (e - 1.f) * __builtin_amdgcn_rcpf(e + 1.f);
}

// ---------------------------------------------------------------------------
// Packed layouts (shared by pack kernels and GEMM staging; identity between
// global group index and LDS linear group index => linear global_load_lds):
//   A (Hbp): group F = ((mt*16+t)*2+kk)*1024 + g*256 + row
//            elems: Hbp[F*8+j] = bf16(H[mt*256+row][t*64+kk*32+g*8+j])
//   B (Wp):  group F = ((nt*16+t)*2+kk)*1024 + g*256 + col
//            elems: Wp[F*8+j]  = bf16(W[t*64+kk*32+g*8+j][nt*256+col])
// Chunk (t,kk) = 1024 groups = 16KB = one LDS slab pair [g(4)][256][16B].

// kernel 0a: pack W -> Wp (2MB read, one-time)
__global__ void wpack_kernel(const float* __restrict__ W, __bf16* __restrict__ Wp) {
    int F   = blockIdx.x * 256 + threadIdx.x;   // 0..65535
    int col = F & 255;
    int g   = (F >> 8) & 3;
    int kk  = (F >> 10) & 1;
    int t   = (F >> 11) & 15;
    int nt  = (F >> 15) & 1;
    int k0  = t * 64 + kk * 32 + g * 8;
    int c   = nt * 256 + col;
    bf16x8 o;
#pragma unroll
    for (int j = 0; j < 8; ++j) o[j] = (__bf16)W[(k0 + j) * 512 + c];
    *reinterpret_cast<bf16x8*>(Wp + (size_t)F * 8) = o;
}

// kernel 0b: convert+pack H (f32, 268MB) -> Hbp (bf16, 134MB, L3-resident after)
// block = (mt, c): 256 threads (r). Thread reads 64B (elems c*16..c*16+15 of
// row mt*256+r) and writes the two 16B groups kg=2c, 2c+1.
__global__ void hcvt_kernel(const float* __restrict__ H, __bf16* __restrict__ Hbp) {
    const int blk = blockIdx.x;                 // 0..16383
    const int mt = blk >> 6, c = blk & 63, r = threadIdx.x;
    const float* src = H + ((size_t)(mt * 256 + r)) * 1024 + c * 16;
    f32x4 v0 = *reinterpret_cast<const f32x4*>(src);
    f32x4 v1 = *reinterpret_cast<const f32x4*>(src + 4);
    f32x4 v2 = *reinterpret_cast<const f32x4*>(src + 8);
    f32x4 v3 = *reinterpret_cast<const f32x4*>(src + 12);
    bf16x8 o0 = {(__bf16)v0.x, (__bf16)v0.y, (__bf16)v0.z, (__bf16)v0.w,
                 (__bf16)v1.x, (__bf16)v1.y, (__bf16)v1.z, (__bf16)v1.w};
    bf16x8 o1 = {(__bf16)v2.x, (__bf16)v2.y, (__bf16)v2.z, (__bf16)v2.w,
                 (__bf16)v3.x, (__bf16)v3.y, (__bf16)v3.z, (__bf16)v3.w};
    // kg = 2c: t=c>>2, kk=(c>>1)&1, g=2(c&1); kg=2c+1: g=2(c&1)+1
    size_t base = ((((size_t)mt * 16 + (c >> 2)) * 2 + ((c >> 1) & 1)) * 4 + (c & 1) * 2);
    *reinterpret_cast<bf16x8*>(Hbp + (base * 256 + r) * 8)       = o0;
    *reinterpret_cast<bf16x8*>(Hbp + ((base + 1) * 256 + r) * 8) = o1;
}

// ---------------------------------------------------------------------------
// kernel 1: 8-phase counted-vmcnt GEMM (m201 template). WG = 256 rows x 256
// cols, 512 thr = 8 waves (2M x 4N), wave tile 128x64 (acc 128 VGPR), BK=64,
// 16 K-steps x 4 phases. LDS 128KB dynamic: dbuf x (A 32KB + B 32KB), slab-
// major [kk][g][256][16B] (conflict-free ds_read_b128 by construction).
// Per phase: ds_read quadrant | issue 1 chunk (2 x gload_lds) for t+1 |
// counted vmcnt at ph1/ph3 | s_barrier | lgkmcnt(0)+sched_barrier |
// setprio(1) 16xMFMA setprio(0) | s_barrier.  vmcnt never drains in-loop.
__global__ __launch_bounds__(512, 2) void score_gemm_kernel(
    const __bf16* __restrict__ Hbp, const __bf16* __restrict__ Wp,
    const float* __restrict__ Bb, const float* __restrict__ Uv,
    float* __restrict__ sp)
{
    extern __shared__ __align__(16) char lds[];
    const int tid  = threadIdx.x;
    const int lane = tid & 63;
    const int wid  = tid >> 6;     // 0..7
    const int c15  = lane & 15;
    const int hi   = lane >> 4;    // 0..3
    const int wr   = wid >> 2;     // 0..1 (M)
    const int wc   = wid & 3;      // 0..3 (N)

    // XCD-bijective swizzle (512 % 8 == 0): both nt of one mt adjacent on XCD
    const int bid = blockIdx.x;
    const int L  = (bid & 7) * 64 + (bid >> 3);
    const int nt = L & 1, mt = L >> 1;

    // staging slots: thread issues 2 gload_lds per chunk
    const int slot0 = wid * 128 + lane;          // group index in chunk
    const int slot1 = slot0 + 64;
    const int d0 = wid * 2048 + lane * 16;       // LDS byte offset in slab
    const int d1 = d0 + 1024;

    // fragment read offsets (within a buffer)
    const int aoff = hi * 4096 + (wr * 128 + c15) * 16;          // + kk*16384 + m*256
    const int boff = 32768 + hi * 4096 + (wc * 64 + c15) * 16;   // + kk*16384 + n*256

#define GLD(srcp, dstoff)                                                      \
    __builtin_amdgcn_global_load_lds(                                          \
        (const __attribute__((address_space(1))) void*)(const void*)(srcp),    \
        (__attribute__((address_space(3))) void*)(void*)(lds + (dstoff)), 16, 0, 0)

#define ISSUE_A(t_, kk_, db_) {                                                \
        size_t gb = (((size_t)mt * 16 + (t_)) * 2 + (kk_)) * 1024;             \
        GLD(Hbp + (gb + slot0) * 8, (db_) * 65536 + (kk_) * 16384 + d0);       \
        GLD(Hbp + (gb + slot1) * 8, (db_) * 65536 + (kk_) * 16384 + d1); }

#define ISSUE_B(t_, kk_, db_) {                                                \
        size_t gb = (((size_t)nt * 16 + (t_)) * 2 + (kk_)) * 1024;             \
        GLD(Wp + (gb + slot0) * 8, (db_) * 65536 + 32768 + (kk_) * 16384 + d0);\
        GLD(Wp + (gb + slot1) * 8, (db_) * 65536 + 32768 + (kk_) * 16384 + d1); }

    f32x4 acc[8][4];
#pragma unroll
    for (int m = 0; m < 8; ++m)
#pragma unroll
        for (int n = 0; n < 4; ++n) acc[m][n] = f32x4{0.f, 0.f, 0.f, 0.f};

#define MFMA_QUAD(mb)                                                          \
    _Pragma("unroll")                                                          \
    for (int m = 0; m < 4; ++m) {                                              \
        _Pragma("unroll")                                                      \
        for (int n = 0; n < 4; ++n)                                            \
            acc[(mb) + m][n] = __builtin_amdgcn_mfma_f32_16x16x32_bf16(        \
                af[m], bf[n], acc[(mb) + m][n], 0, 0, 0);                      \
    }

#define PHASE_TAIL(mb)                                                         \
    __builtin_amdgcn_s_barrier();                                              \
    asm volatile("s_waitcnt lgkmcnt(0)" ::: "memory");                         \
    __builtin_amdgcn_sched_barrier(0);                                         \
    __builtin_amdgcn_s_setprio(1);                                             \
    MFMA_QUAD(mb);                                                             \
    __builtin_amdgcn_s_setprio(0);                                             \
    __builtin_amdgcn_s_barrier();

    // ---- prologue: stage all 4 chunks of t=0 into buf0 (8 loads)
    ISSUE_A(0, 0, 0); ISSUE_B(0, 0, 0); ISSUE_A(0, 1, 0); ISSUE_B(0, 1, 0);
    asm volatile("s_waitcnt vmcnt(4)" ::: "memory");   // A0,B0 landed (mine)
    __builtin_amdgcn_s_barrier();                       // ...collectively

    for (int t = 0; t < 16; ++t) {
        const int db = t & 1, nb = db ^ 1;
        const char* abase = lds + db * 65536;
        bf16x8 af[4], bf[4];

        // ---- phase 0: kk=0, m 0..3 (+ read B kk0)
#pragma unroll
        for (int n = 0; n < 4; ++n)
            bf[n] = *reinterpret_cast<const bf16x8*>(abase + boff + n * 256);
#pragma unroll
        for (int m = 0; m < 4; ++m)
            af[m] = *reinterpret_cast<const bf16x8*>(abase + aoff + m * 256);
        if (t < 15) ISSUE_A(t + 1, 0, nb);
        PHASE_TAIL(0);

        // ---- phase 1: kk=0, m 4..7 (reuse bf); wait covers THIS step's kk1
#pragma unroll
        for (int m = 0; m < 4; ++m)
            af[m] = *reinterpret_cast<const bf16x8*>(abase + aoff + 1024 + m * 256);
        if (t < 15) {
            ISSUE_B(t + 1, 0, nb);
            asm volatile("s_waitcnt vmcnt(4)" ::: "memory"); // t's A1,B1 landed
        } else {
            asm volatile("s_waitcnt vmcnt(0)" ::: "memory");
        }
        PHASE_TAIL(4);

        // ---- phase 2: kk=1, m 0..3 (+ read B kk1)
#pragma unroll
        for (int n = 0; n < 4; ++n)
            bf[n] = *reinterpret_cast<const bf16x8*>(abase + 16384 + boff + n * 256);
#pragma unroll
        for (int m = 0; m < 4; ++m)
            af[m] = *reinterpret_cast<const bf16x8*>(abase + 16384 + aoff + m * 256);
        if (t < 15) ISSUE_A(t + 1, 1, nb);
        PHASE_TAIL(0);

        // ---- phase 3: kk=1, m 4..7; wait covers NEXT step's kk0
#pragma unroll
        for (int m = 0; m < 4; ++m)
            af[m] = *reinterpret_cast<const bf16x8*>(abase + 16384 + aoff + 1024 + m * 256);
        if (t < 15) {
            ISSUE_B(t + 1, 1, nb);
            asm volatile("s_waitcnt vmcnt(4)" ::: "memory"); // t+1's A0,B0 landed
        }
        PHASE_TAIL(4);
    }
    __syncthreads();   // full drain before LDS reuse

    // ---- epilogue: tanh(acc + bias)*U, reduce over the WG's 256 cols
    float bias[4], uu[4];
#pragma unroll
    for (int n = 0; n < 4; ++n) {
        int col = nt * 256 + wc * 64 + n * 16 + c15;
        bias[n] = Bb[col];
        uu[n]   = Uv[col];
    }
    float* partial = reinterpret_cast<float*>(lds);  // [4 wc][256 rows]
#pragma unroll
    for (int m = 0; m < 8; ++m) {
        float pr[4];
#pragma unroll
        for (int r = 0; r < 4; ++r) pr[r] = 0.f;
#pragma unroll
        for (int n = 0; n < 4; ++n)
#pragma unroll
            for (int r = 0; r < 4; ++r)
                pr[r] += tanh_fast(acc[m][n][r] + bias[n]) * uu[n];
#pragma unroll
        for (int r = 0; r < 4; ++r) {
            float v = pr[r];
            v += __shfl_xor(v, 1); v += __shfl_xor(v, 2);
            v += __shfl_xor(v, 4); v += __shfl_xor(v, 8);
            if (c15 == 0)
                partial[wc * 256 + wr * 128 + m * 16 + hi * 4 + r] = v;
        }
    }
    __syncthreads();
    if (tid < 256) {
        float sc = (partial[tid] + partial[256 + tid]) +
                   (partial[512 + tid] + partial[768 + tid]);
        sp[(size_t)nt * NROWS + (size_t)mt * 256 + tid] = sc;
    }
}

// ---------------------------------------------------------------------------
// kernel 2: per-batch softmax over n=2048 (scores = sum of 2 N-partials)
__global__ void softmax_kernel(const float* __restrict__ sp, float* __restrict__ VU) {
    __shared__ float red[8];
    const int b = blockIdx.x, tid = threadIdx.x;
    const int lane = tid & 63, wid = tid >> 6;
    float v[8];
    float mx = -3.0e38f;
#pragma unroll
    for (int j = 0; j < 8; ++j) {
        int x = b * N_SEQ + tid + j * 256;
        v[j] = sp[x] + sp[NROWS + x];
        mx = fmaxf(mx, v[j]);
    }
#pragma unroll
    for (int off = 1; off < 64; off <<= 1) mx = fmaxf(mx, __shfl_xor(mx, off));
    if (lane == 0) red[wid] = mx;
    __syncthreads();
    mx = fmaxf(fmaxf(red[0], red[1]), fmaxf(red[2], red[3]));
    float e[8], sum = 0.f;
#pragma unroll
    for (int j = 0; j < 8; ++j) { e[j] = __expf(v[j] - mx); sum += e[j]; }
#pragma unroll
    for (int off = 1; off < 64; off <<= 1) sum += __shfl_xor(sum, off);
    if (lane == 0) red[4 + wid] = sum;
    __syncthreads();
    float total = (red[4] + red[5]) + (red[6] + red[7]);
    float rinv = 1.f / total;
#pragma unroll
    for (int j = 0; j < 8; ++j) VU[b * N_SEQ + tid + j * 256] = e[j] * rinv;
}

// ---------------------------------------------------------------------------
// kernel 3: Ma = H * VU (broadcast over u), float4 vectorized
__global__ void ma_kernel(const float* __restrict__ H, const float* __restrict__ VU,
                          float* __restrict__ Ma) {
    const int stride = gridDim.x * blockDim.x;
    const int n4 = (int)(MA_ELEMS / 4);
    for (int i4 = blockIdx.x * blockDim.x + threadIdx.x; i4 < n4; i4 += stride) {
        float sc = VU[i4 >> 8];                         // 256 float4 per row
        f32x4 h = reinterpret_cast<const f32x4*>(H)[i4];
        reinterpret_cast<f32x4*>(Ma)[i4] = h * sc;
    }
}

// ---------------------------------------------------------------------------
extern "C" void kernel_launch(void* const* d_in, const int* in_sizes, int n_in,
                              void* d_out, int out_size, void* d_ws, size_t ws_size,
                              hipStream_t stream) {
    const float* H  = (const float*)d_in[0];
    const float* W  = (const float*)d_in[1];
    const float* Bb = (const float*)d_in[2];
    const float* Uv = (const float*)d_in[3];

    float* out = (float*)d_out;
    float* Ma  = out;                          // 67108864 floats
    float* VU  = out + MA_ELEMS;               // 65536 floats
    // scratch inside the Ma region (ma_kernel overwrites it all at the end):
    float*  sp  = out;                         // 2 x 65536 partial scores
    __bf16* Wp  = (__bf16*)(out + 131072);     // 524288 bf16 (1MB)
    __bf16* Hbp = (__bf16*)(out + 1048576);    // 67108864 bf16 (134MB)

    hipFuncSetAttribute((const void*)score_gemm_kernel,
                        hipFuncAttributeMaxDynamicSharedMemorySize, 131072);

    wpack_kernel<<<256, 256, 0, stream>>>(W, Wp);
    hcvt_kernel<<<16384, 256, 0, stream>>>(H, Hbp);
    score_gemm_kernel<<<512, 512, 131072, stream>>>(Hbp, Wp, Bb, Uv, sp);
    softmax_kernel<<<N_BATCH, 256, 0, stream>>>(sp, VU);
    ma_kernel<<<2048, 256, 0, stream>>>(H, VU, Ma);
}

// Round 5
// 168.398 us; speedup vs baseline: 1.7787x; 1.7787x over previous
//
#include <hip/hip_runtime.h>
#include <hip/hip_bf16.h>

typedef __attribute__((ext_vector_type(8))) __bf16 bf16x8;
typedef __attribute__((ext_vector_type(4))) float f32x4;

#define N_SEQ   2048
#define N_BATCH 32
#define DIM_U   1024
#define NROWS   65536
#define MA_ELEMS ((size_t)NROWS * DIM_U) /* 67108864 */

__device__ __forceinline__ float tanh_fast(float x) {
    x = fminf(fmaxf(x, -15.f), 15.f);
    float e = __expf(2.f * x);
    return (e - 1.f) * __builtin_amdgcn_rcpf(e + 1.f);
}

// ---------------------------------------------------------------------------
// kernel 0: pack W (1024x512 f32) -> bf16, B-stage order.
// F = ((it*2+nh)*4+g)*256+col (it 0..31, g 0..3); elem j: k=it*32+g*8+j,
// c=nh*256+col. Chunk (it,nh) = 1024 groups = 16KB = one LDS B-slab
// [g][col256][16B], global order == LDS linear order (gload_lds identity).
__global__ void wpack_kernel(const float* __restrict__ W, __bf16* __restrict__ Wp) {
    int F   = blockIdx.x * 256 + threadIdx.x;   // 0..65535
    int col = F & 255;
    int g   = (F >> 8) & 3;
    int nh  = (F >> 10) & 1;
    int it  = F >> 11;
    int k0  = it * 32 + g * 8;
    int c   = nh * 256 + col;
    bf16x8 o;
#pragma unroll
    for (int j = 0; j < 8; ++j) o[j] = (__bf16)W[(k0 + j) * 512 + c];
    *reinterpret_cast<bf16x8*>(Wp + (size_t)F * 8) = o;
}

// ---------------------------------------------------------------------------
// kernel 1: partial scores. WG = 128 rows x 256 cols, K=1024, BK=32, 32 iters.
// 512 thr = 8 waves (2M x 4N), wave 64x64 (acc 64 VGPR). LDS 48KB:
// A dbuf 2x8KB [g][row^g XOR-swz][16B], B dbuf 2x16KB [g][col][16B].
// 2-phase, ONE barrier/iter, counted vmcnt(2) (A-reg prefetch stays in
// flight; B gload_lds landed). A f32->bf16 converted in-reg (T14 split:
// load 2 iters ahead, write 1 iter ahead).
__global__ __launch_bounds__(512, 4) void score_gemm_kernel(
    const float* __restrict__ H, const __bf16* __restrict__ Wp,
    const float* __restrict__ Bb, const float* __restrict__ Uv,
    float* __restrict__ sp)
{
    __shared__ __align__(16) char lds[49152];
    const int tid  = threadIdx.x;
    const int lane = tid & 63;
    const int wid  = tid >> 6;     // 0..7
    const int c15  = lane & 15;
    const int hi   = lane >> 4;    // 0..3
    const int wr   = wid >> 2;     // 0..1 (M)
    const int wc   = wid & 3;      // 0..3 (N)

    // XCD-bijective swizzle (1024 % 8 == 0): (mt,nh) pairs adjacent on an XCD
    const int bid = blockIdx.x;
    const int L   = (bid & 7) * 128 + (bid >> 3);
    const int mt = L >> 1, nh = L & 1;
    const long rowbase = (long)mt * 128;

    // A staging: thread covers row=tid>>2, g=tid&3 (8 f32 -> 1 bf16x8)
    const int arow = tid >> 2, ag = tid & 3;
    const float* aglob = H + (rowbase + arow) * DIM_U + ag * 8;
    const int awoff = ag * 2048 + ((arow ^ ag) * 16);      // + db*8192

    // frag read bases
    const int abase0 = hi * 2048 + (wr * 64 + (c15 ^ hi)) * 16;   // + db*8192 + m*256
    const int bbase0 = 16384 + hi * 4096 + (wc * 64 + c15) * 16;  // + db*16384 + n*256

#define GLD(srcp, dstoff)                                                      \
    __builtin_amdgcn_global_load_lds(                                          \
        (const __attribute__((address_space(1))) void*)(const void*)(srcp),    \
        (__attribute__((address_space(3))) void*)(void*)(lds + (dstoff)), 16, 0, 0)

#define STAGE_B(it_, db_) {                                                    \
        const __bf16* bg_ = Wp + (((size_t)(it_) * 2 + nh) * 1024) * 8;        \
        GLD(bg_ + (size_t)tid * 8,         16384 + (db_) * 16384 + tid * 16);  \
        GLD(bg_ + ((size_t)tid + 512) * 8, 16384 + (db_) * 16384 + 8192 + tid * 16); }

#define LOADA(La_, Lb_, it_) {                                                 \
        const float* p_ = aglob + (it_) * 32;                                  \
        La_ = *reinterpret_cast<const f32x4*>(p_);                             \
        Lb_ = *reinterpret_cast<const f32x4*>(p_ + 4); }

#define CVTW(La_, Lb_, db_) {                                                  \
        bf16x8 pk_ = {(__bf16)La_.x, (__bf16)La_.y, (__bf16)La_.z,             \
                      (__bf16)La_.w, (__bf16)Lb_.x, (__bf16)Lb_.y,             \
                      (__bf16)Lb_.z, (__bf16)Lb_.w};                           \
        *reinterpret_cast<bf16x8*>(lds + (db_) * 8192 + awoff) = pk_; }

#define COMPUTE(db_) {                                                         \
        bf16x8 af[4], bf[4];                                                   \
        _Pragma("unroll")                                                      \
        for (int m = 0; m < 4; ++m)                                            \
            af[m] = *reinterpret_cast<const bf16x8*>(                          \
                lds + (db_) * 8192 + abase0 + m * 256);                        \
        _Pragma("unroll")                                                      \
        for (int n = 0; n < 4; ++n)                                            \
            bf[n] = *reinterpret_cast<const bf16x8*>(                          \
                lds + (db_) * 16384 + bbase0 + n * 256);                       \
        __builtin_amdgcn_s_setprio(1);                                         \
        _Pragma("unroll")                                                      \
        for (int m = 0; m < 4; ++m) {                                          \
            _Pragma("unroll")                                                  \
            for (int n = 0; n < 4; ++n)                                        \
                acc[m][n] = __builtin_amdgcn_mfma_f32_16x16x32_bf16(           \
                    af[m], bf[n], acc[m][n], 0, 0, 0);                         \
        }                                                                      \
        __builtin_amdgcn_s_setprio(0); }

#define WAITBAR2 { asm volatile("s_waitcnt vmcnt(2) lgkmcnt(0)" ::: "memory"); \
                   __builtin_amdgcn_s_barrier(); }
#define WAITBAR0 { asm volatile("s_waitcnt vmcnt(0) lgkmcnt(0)" ::: "memory"); \
                   __builtin_amdgcn_s_barrier(); }

    f32x4 acc[4][4];
#pragma unroll
    for (int m = 0; m < 4; ++m)
#pragma unroll
        for (int n = 0; n < 4; ++n) acc[m][n] = f32x4{0.f, 0.f, 0.f, 0.f};

    f32x4 L0a, L0b, L1a, L1b;

    // ---- prologue: A(0)+B(0) -> buf0; A(1) in flight
    LOADA(L0a, L0b, 0);
    CVTW(L0a, L0b, 0);                  // compiler waits on L0 here
    STAGE_B(0, 0);
    __builtin_amdgcn_sched_barrier(0);
    LOADA(L1a, L1b, 1);
    __builtin_amdgcn_sched_barrier(0);
    WAITBAR2;                            // B(0) landed; A(1) flying

    // ---- main loop: iters 0..29 (pairs), peeled 30/31
    for (int tt = 0; tt < 15; ++tt) {
        const int t0 = 2 * tt;
        // even iter t0: read buf0, stage buf1
        STAGE_B(t0 + 1, 1);
        __builtin_amdgcn_sched_barrier(0);
        LOADA(L0a, L0b, t0 + 2);
        __builtin_amdgcn_sched_barrier(0);
        COMPUTE(0);
        CVTW(L1a, L1b, 1);               // A(t0+1)
        WAITBAR2;
        // odd iter t0+1: read buf1, stage buf0
        STAGE_B(t0 + 2, 0);
        __builtin_amdgcn_sched_barrier(0);
        LOADA(L1a, L1b, t0 + 3);
        __builtin_amdgcn_sched_barrier(0);
        COMPUTE(1);
        CVTW(L0a, L0b, 0);               // A(t0+2)
        WAITBAR2;
    }
    // iter 30 (reads buf0, stages buf1)
    STAGE_B(31, 1);
    COMPUTE(0);
    CVTW(L1a, L1b, 1);                   // A(31)
    WAITBAR0;
    // iter 31 (reads buf1)
    COMPUTE(1);

    // ---- epilogue: tanh(acc + bias)*U, reduce over the WG's 256 cols
    float bias[4], uu[4];
#pragma unroll
    for (int n = 0; n < 4; ++n) {
        int col = nh * 256 + wc * 64 + n * 16 + c15;
        bias[n] = Bb[col];
        uu[n]   = Uv[col];
    }
    float* partial = reinterpret_cast<float*>(lds);  // [4 wc][128 rows]
#pragma unroll
    for (int m = 0; m < 4; ++m) {
        float pr[4];
#pragma unroll
        for (int r = 0; r < 4; ++r) pr[r] = 0.f;
#pragma unroll
        for (int n = 0; n < 4; ++n)
#pragma unroll
            for (int r = 0; r < 4; ++r)
                pr[r] += tanh_fast(acc[m][n][r] + bias[n]) * uu[n];
#pragma unroll
        for (int r = 0; r < 4; ++r) {
            float v = pr[r];
            v += __shfl_xor(v, 1); v += __shfl_xor(v, 2);
            v += __shfl_xor(v, 4); v += __shfl_xor(v, 8);
            if (c15 == 0)
                partial[wc * 128 + wr * 64 + m * 16 + hi * 4 + r] = v;
        }
    }
    __syncthreads();
    if (tid < 128) {
        float sc = (partial[tid] + partial[128 + tid]) +
                   (partial[256 + tid] + partial[384 + tid]);
        sp[(size_t)nh * NROWS + rowbase + tid] = sc;
    }
}

// ---------------------------------------------------------------------------
// kernel 2: per-batch softmax over n=2048 (scores = sum of 2 N-partials)
__global__ void softmax_kernel(const float* __restrict__ sp, float* __restrict__ VU) {
    __shared__ float red[8];
    const int b = blockIdx.x, tid = threadIdx.x;
    const int lane = tid & 63, wid = tid >> 6;
    float v[8];
    float mx = -3.0e38f;
#pragma unroll
    for (int j = 0; j < 8; ++j) {
        int x = b * N_SEQ + tid + j * 256;
        v[j] = sp[x] + sp[NROWS + x];
        mx = fmaxf(mx, v[j]);
    }
#pragma unroll
    for (int off = 1; off < 64; off <<= 1) mx = fmaxf(mx, __shfl_xor(mx, off));
    if (lane == 0) red[wid] = mx;
    __syncthreads();
    mx = fmaxf(fmaxf(red[0], red[1]), fmaxf(red[2], red[3]));
    float e[8], sum = 0.f;
#pragma unroll
    for (int j = 0; j < 8; ++j) { e[j] = __expf(v[j] - mx); sum += e[j]; }
#pragma unroll
    for (int off = 1; off < 64; off <<= 1) sum += __shfl_xor(sum, off);
    if (lane == 0) red[4 + wid] = sum;
    __syncthreads();
    float total = (red[4] + red[5]) + (red[6] + red[7]);
    float rinv = 1.f / total;
#pragma unroll
    for (int j = 0; j < 8; ++j) VU[b * N_SEQ + tid + j * 256] = e[j] * rinv;
}

// ---------------------------------------------------------------------------
// kernel 3: Ma = H * VU (broadcast over u); nontemporal stores (write-once)
__global__ void ma_kernel(const float* __restrict__ H, const float* __restrict__ VU,
                          float* __restrict__ Ma) {
    const int stride = gridDim.x * blockDim.x;
    const int n4 = (int)(MA_ELEMS / 4);
    for (int i4 = blockIdx.x * blockDim.x + threadIdx.x; i4 < n4; i4 += stride) {
        float sc = VU[i4 >> 8];                         // 256 float4 per row
        f32x4 h = reinterpret_cast<const f32x4*>(H)[i4];
        __builtin_nontemporal_store(h * sc, reinterpret_cast<f32x4*>(Ma) + i4);
    }
}

// ---------------------------------------------------------------------------
extern "C" void kernel_launch(void* const* d_in, const int* in_sizes, int n_in,
                              void* d_out, int out_size, void* d_ws, size_t ws_size,
                              hipStream_t stream) {
    const float* H  = (const float*)d_in[0];
    const float* W  = (const float*)d_in[1];
    const float* Bb = (const float*)d_in[2];
    const float* Uv = (const float*)d_in[3];

    float* out = (float*)d_out;
    float* Ma  = out;                          // 67108864 floats
    float* VU  = out + MA_ELEMS;               // 65536 floats
    // scratch inside the Ma region (ma_kernel overwrites it all at the end):
    float*  sp = out;                          // 2 x 65536 partial scores
    __bf16* Wp = (__bf16*)(out + 131072);      // 524288 bf16 (1MB)

    wpack_kernel<<<256, 256, 0, stream>>>(W, Wp);
    score_gemm_kernel<<<1024, 512, 0, stream>>>(H, Wp, Bb, Uv, sp);
    softmax_kernel<<<N_BATCH, 256, 0, stream>>>(sp, VU);
    ma_kernel<<<2048, 256, 0, stream>>>(H, VU, Ma);
}